// Round 2
// baseline (334.928 us; speedup 1.0000x reference)
//
#include <hip/hip_runtime.h>

#define BATCH 200000
#define ITERS 100
#define NPTS 101      // 1 init point + 100 steps
#define TC 16         // points staged per chunk
#define BLK 256

// One thread per batch element. Serial scan in registers; trajectory points
// staged in LDS (padded rows, conflict-free) and written out coalesced:
// 32 consecutive lanes cover one element's contiguous 128B segment.
__launch_bounds__(BLK, 4)
__global__ void ifs_traj_kernel(const float* __restrict__ coef,
                                const float* __restrict__ h,
                                float* __restrict__ out) {
    // 33-float row pitch: (33*tid + 2i) % 32 == (tid + 2i) % 32 -> 2 lanes/bank (free)
    __shared__ float lds[BLK * 33];

    const int tid = threadIdx.x;
    const int b0  = blockIdx.x * BLK;
    const int b   = b0 + tid;
    const int bl  = (b < BATCH) ? b : (BATCH - 1);   // clamp for safe loads

    // 12 coefs as 3 aligned float4 (row = 48B, 16B-aligned)
    const float4* c4 = (const float4*)(coef + (size_t)bl * 12);
    const float4 ca0 = c4[0];   // c0 c1 c2 c3
    const float4 ca1 = c4[1];   // c4 c5 c6 c7
    const float4 ca2 = c4[2];   // c8 c9 c10 c11

    const float j0 = fabsf(ca0.x * ca0.w - ca0.y * ca0.z);
    const float j1 = fabsf(ca1.z * ca2.y - ca1.w * ca2.x);
    const float p  = j0 / (j0 + j1);

    float x = 0.05f, y = 0.05f;
    float* row = lds + tid * 33;

    const int jj   = tid & 31;   // float index within an element's segment
    const int esub = tid >> 5;   // which of 8 elements this iteration

    for (int cs = 0; cs < NPTS; cs += TC) {
        const int n = (NPTS - cs < TC) ? (NPTS - cs) : TC;   // uniform across block

        #pragma unroll
        for (int i = 0; i < TC; ++i) {
            if (i < n) {
                const int pt = cs + i;          // uniform -> scalar branch
                if (pt > 0) {
                    const float ht = h[(size_t)(pt - 1) * BATCH + bl];
                    const bool useB = ht > p;
                    const float m0 = useB ? ca1.z : ca0.x;
                    const float m1 = useB ? ca1.w : ca0.y;
                    const float m2 = useB ? ca2.x : ca0.z;
                    const float m3 = useB ? ca2.y : ca0.w;
                    const float m4 = useB ? ca2.z : ca1.x;
                    const float m5 = useB ? ca2.w : ca1.y;
                    const float xn = fmaf(m0, x, fmaf(m1, y, m4));
                    const float yn = fmaf(m2, x, fmaf(m3, y, m5));
                    x = xn; y = yn;
                }
                row[2 * i]     = x;
                row[2 * i + 1] = y;
            }
        }
        __syncthreads();

        // Cooperative coalesced write: per iteration, 8 elements x 32 floats.
        // Lanes 0..31 -> element ebase+esub (contiguous 128B), lanes 32..63 -> next.
        const int nf = 2 * n;                    // floats this chunk (<=32)
        for (int ebase = 0; ebase < BLK; ebase += 8) {
            const int e  = ebase + esub;
            const int gb = b0 + e;
            if (jj < nf && gb < BATCH) {
                out[(size_t)gb * (2 * NPTS) + 2 * cs + jj] = lds[e * 33 + jj];
            }
        }
        __syncthreads();
    }
}

extern "C" void kernel_launch(void* const* d_in, const int* in_sizes, int n_in,
                              void* d_out, int out_size, void* d_ws, size_t ws_size,
                              hipStream_t stream) {
    const float* coef = (const float*)d_in[0];   // (BATCH, 12) f32
    const float* h    = (const float*)d_in[1];   // (ITERS, BATCH) f32
    float* out        = (float*)d_out;           // (BATCH, 101, 2) f32

    const int grid = (BATCH + BLK - 1) / BLK;    // 782
    ifs_traj_kernel<<<grid, BLK, 0, stream>>>(coef, h, out);
}

// Round 3
// 327.906 us; speedup vs baseline: 1.0214x; 1.0214x over previous
//
#include <hip/hip_runtime.h>

#define BATCH 200000
#define ITERS 100
#define NPTS 101      // 1 init point + 100 steps
#define TC 16         // points staged per chunk
#define NCHUNK 7      // ceil(NPTS / TC)
#define BLK 256

// Raw barrier: drain LDS ops only (lgkmcnt), leave global loads/stores in
// flight across the barrier (HK pattern — avoids the compiler's vmcnt(0)
// drain that __syncthreads() emits). Correctness: cross-thread data flows
// only through LDS here; global stores target disjoint addresses and
// prefetched h-loads land in private VGPRs.
__device__ __forceinline__ void bar_lgkm() {
    asm volatile("s_waitcnt lgkmcnt(0)" ::: "memory");
    __builtin_amdgcn_s_barrier();
    asm volatile("" ::: "memory");
}

__launch_bounds__(BLK, 4)
__global__ void ifs_traj_kernel(const float* __restrict__ coef,
                                const float* __restrict__ h,
                                float* __restrict__ out) {
    // 33-float row pitch: ds_write banks (33*tid+2i)%32 -> 2 lanes/bank (free);
    // store-loop ds_read also conflict-free (verified: 0 SQ_LDS_BANK_CONFLICT).
    __shared__ float lds[BLK * 33];

    const int tid = threadIdx.x;
    const int b0  = blockIdx.x * BLK;
    const int b   = b0 + tid;
    const int bl  = (b < BATCH) ? b : (BATCH - 1);   // clamp for safe loads

    const float4* c4 = (const float4*)(coef + (size_t)bl * 12);
    const float4 ca0 = c4[0];   // c0 c1 c2 c3
    const float4 ca1 = c4[1];   // c4 c5 c6 c7
    const float4 ca2 = c4[2];   // c8 c9 c10 c11

    const float j0 = fabsf(ca0.x * ca0.w - ca0.y * ca0.z);
    const float j1 = fabsf(ca1.z * ca2.y - ca1.w * ca2.x);
    const float p  = j0 / (j0 + j1);

    float x = 0.05f, y = 0.05f;
    float* row = lds + tid * 33;

    const int jj   = tid & 31;   // float index within an element's 128B segment
    const int esub = tid >> 5;

    float hA[TC], hB[TC];

    // Prologue: h for chunk 0 (points 1..15 need h rows 0..14)
    #pragma unroll
    for (int i = 1; i < TC; ++i) {
        hA[i] = h[(size_t)(i - 1) * BATCH + bl];
    }

    // One chunk: prefetch next h into hN, compute points cs..cs+TC-1 from hC,
    // stage in LDS, cooperative coalesced store. Called with literal c so all
    // array indices are compile-time (registers, not scratch).
    auto do_chunk = [&](int c, float (&hC)[TC], float (&hN)[TC], bool pref) {
        const int cs = c * TC;

        if (pref) {
            #pragma unroll
            for (int i = 0; i < TC; ++i) {
                const int pt = cs + TC + i;        // >= 16, so pt-1 >= 15 valid
                if (pt < NPTS) hN[i] = h[(size_t)(pt - 1) * BATCH + bl];
            }
        }

        #pragma unroll
        for (int i = 0; i < TC; ++i) {
            const int pt = cs + i;                 // uniform -> scalar branch
            if (pt >= 1 && pt < NPTS) {
                const float ht = hC[i];
                const bool useB = ht > p;
                const float m0 = useB ? ca1.z : ca0.x;
                const float m1 = useB ? ca1.w : ca0.y;
                const float m2 = useB ? ca2.x : ca0.z;
                const float m3 = useB ? ca2.y : ca0.w;
                const float m4 = useB ? ca2.z : ca1.x;
                const float m5 = useB ? ca2.w : ca1.y;
                const float xn = fmaf(m0, x, fmaf(m1, y, m4));
                const float yn = fmaf(m2, x, fmaf(m3, y, m5));
                x = xn; y = yn;
            }
            if (pt < NPTS) {
                row[2 * i]     = x;
                row[2 * i + 1] = y;
            }
        }

        bar_lgkm();   // publish LDS writes; stores/loads stay in flight

        const int n  = (NPTS - cs < TC) ? (NPTS - cs) : TC;
        const int nf = 2 * n;                      // <= 32 floats per element
        for (int ebase = 0; ebase < BLK; ebase += 8) {
            const int e  = ebase + esub;
            const int gb = b0 + e;
            if (jj < nf && gb < BATCH) {
                out[(size_t)gb * (2 * NPTS) + 2 * cs + jj] = lds[e * 33 + jj];
            }
        }

        bar_lgkm();   // all lanes' ds_reads done before next chunk overwrites LDS
    };

    do_chunk(0, hA, hB, true);
    do_chunk(1, hB, hA, true);
    do_chunk(2, hA, hB, true);
    do_chunk(3, hB, hA, true);
    do_chunk(4, hA, hB, true);
    do_chunk(5, hB, hA, true);
    do_chunk(6, hA, hB, false);   // points 96..100 (nf = 10)
}

extern "C" void kernel_launch(void* const* d_in, const int* in_sizes, int n_in,
                              void* d_out, int out_size, void* d_ws, size_t ws_size,
                              hipStream_t stream) {
    const float* coef = (const float*)d_in[0];   // (BATCH, 12) f32
    const float* h    = (const float*)d_in[1];   // (ITERS, BATCH) f32
    float* out        = (float*)d_out;           // (BATCH, 101, 2) f32

    const int grid = (BATCH + BLK - 1) / BLK;    // 782
    ifs_traj_kernel<<<grid, BLK, 0, stream>>>(coef, h, out);
}

// Round 5
// 314.858 us; speedup vs baseline: 1.0637x; 1.0414x over previous
//
#include <hip/hip_runtime.h>

#define BATCH 200000
#define ITERS 100
#define NPTS 101      // 1 init point + 100 steps
#define TC 16         // points staged per chunk
#define BLK 256
#define PITCH 34      // even pitch -> 8B-aligned b64 LDS ops; 4 words/bank (optimal)

// Raw barrier draining LDS ops only; global loads/stores stay in flight
// (cross-thread data flows only through LDS; global stores are disjoint).
__device__ __forceinline__ void bar_lgkm() {
    asm volatile("s_waitcnt lgkmcnt(0)" ::: "memory");
    __builtin_amdgcn_s_barrier();
    asm volatile("" ::: "memory");
}

// min 3 waves/EU = 12 waves/CU (exactly the grid-bound occupancy) -> VGPR cap ~168,
// giving the scheduler room to batch 16 ds_read_b64 results before the stores.
__launch_bounds__(BLK, 3)
__global__ void ifs_traj_kernel(const float* __restrict__ coef,
                                const float* __restrict__ h,
                                float* __restrict__ out) {
    __shared__ float lds[BLK * PITCH];

    const int tid = threadIdx.x;
    const int b0  = blockIdx.x * BLK;
    const int b   = b0 + tid;
    const int bl  = (b < BATCH) ? b : (BATCH - 1);   // clamp for safe loads

    const float4* c4 = (const float4*)(coef + (size_t)bl * 12);
    const float4 ca0 = c4[0];   // c0 c1 c2 c3
    const float4 ca1 = c4[1];   // c4 c5 c6 c7
    const float4 ca2 = c4[2];   // c8 c9 c10 c11

    const float j0 = fabsf(ca0.x * ca0.w - ca0.y * ca0.z);
    const float j1 = fabsf(ca1.z * ca2.y - ca1.w * ca2.x);
    const float p  = j0 / (j0 + j1);

    float x = 0.05f, y = 0.05f;
    float2* row2 = (float2*)(lds + tid * PITCH);     // byte 136*tid: 8B-aligned

    const int jj2  = tid & 15;   // float2 index within an element's 128B segment
    const int esub = tid >> 4;   // 4 elements covered per wave per store instr

    float hA[TC], hB[TC];

    // Prologue: h for chunk 0 (points 1..15 need h rows 0..14)
    #pragma unroll
    for (int i = 1; i < TC; ++i) {
        hA[i] = h[(size_t)(i - 1) * BATCH + bl];
    }

    // Called with literal c -> all indices compile-time (registers, not scratch).
    auto do_chunk = [&](int c, float (&hC)[TC], float (&hN)[TC], bool pref) {
        const int cs = c * TC;

        if (pref) {
            #pragma unroll
            for (int i = 0; i < TC; ++i) {
                const int pt = cs + TC + i;          // pt-1 >= 15: valid rows
                if (pt < NPTS) hN[i] = h[(size_t)(pt - 1) * BATCH + bl];
            }
        }

        #pragma unroll
        for (int i = 0; i < TC; ++i) {
            const int pt = cs + i;                   // compile-time per call site
            if (pt >= 1 && pt < NPTS) {
                const float ht = hC[i];
                const bool useB = ht > p;
                const float m0 = useB ? ca1.z : ca0.x;
                const float m1 = useB ? ca1.w : ca0.y;
                const float m2 = useB ? ca2.x : ca0.z;
                const float m3 = useB ? ca2.y : ca0.w;
                const float m4 = useB ? ca2.z : ca1.x;
                const float m5 = useB ? ca2.w : ca1.y;
                const float xn = fmaf(m0, x, fmaf(m1, y, m4));
                const float yn = fmaf(m2, x, fmaf(m3, y, m5));
                x = xn; y = yn;
            }
            if (pt < NPTS) {
                row2[i] = make_float2(x, y);         // ds_write_b64
            }
        }

        bar_lgkm();   // publish LDS writes; global ops stay in flight

        const int n  = (NPTS - cs < TC) ? (NPTS - cs) : TC;
        const int w2 = n;                            // float2 count = n points
        // Coalesced transposed store: per instr, 64 lanes x 8B cover 4 elements'
        // contiguous 128B segments. 16 iterations cover the block's 256 elements.
        #pragma unroll
        for (int ebase = 0; ebase < BLK; ebase += 16) {
            const int e  = ebase + esub;
            const int gb = b0 + e;
            if (jj2 < w2 && gb < BATCH) {
                *(float2*)(out + (size_t)gb * (2 * NPTS) + 2 * cs + 2 * jj2) =
                    *(const float2*)(lds + e * PITCH + 2 * jj2);   // ds_read_b64
            }
        }

        bar_lgkm();   // ds_reads done before next chunk overwrites LDS
    };

    do_chunk(0, hA, hB, true);
    do_chunk(1, hB, hA, true);
    do_chunk(2, hA, hB, true);
    do_chunk(3, hB, hA, true);
    do_chunk(4, hA, hB, true);
    do_chunk(5, hB, hA, true);
    do_chunk(6, hA, hB, false);   // points 96..100 (w2 = 5)
}

extern "C" void kernel_launch(void* const* d_in, const int* in_sizes, int n_in,
                              void* d_out, int out_size, void* d_ws, size_t ws_size,
                              hipStream_t stream) {
    const float* coef = (const float*)d_in[0];   // (BATCH, 12) f32
    const float* h    = (const float*)d_in[1];   // (ITERS, BATCH) f32
    float* out        = (float*)d_out;           // (BATCH, 101, 2) f32

    const int grid = (BATCH + BLK - 1) / BLK;    // 782
    ifs_traj_kernel<<<grid, BLK, 0, stream>>>(coef, h, out);
}

// Round 6
// 237.800 us; speedup vs baseline: 1.4084x; 1.3241x over previous
//
#include <hip/hip_runtime.h>

#define BATCH 200000
#define ITERS 100
#define NPTS 101
#define BLK 64                    // 1 wave; 64 elements per block
#define ROWF 202                  // floats per element row (101 pts * 2), 808 B
#define SPANB (BLK * ROWF * 4)    // 51712 B per block; block base is 64B-aligned
#define FULLR (SPANB / 1024)      // 50 full 1024B sweep rounds
#define TAILV ((SPANB - FULLR * 1024) / 16)   // 32 tail float4s

// One wave per block. Each thread scans its element fully into LDS at exact
// 808B pitch (write pattern = exactly 4 words/bank: conflict-free), then the
// block emits one contiguous 51712B dwordx4 stream -> all full cache lines
// (kills the 20% WRITE_SIZE RMW overhead), 50 KB of stores in flight per wave.
__global__ void ifs_traj_kernel(const float* __restrict__ coef,
                                const float* __restrict__ h,
                                float* __restrict__ out) {
    __shared__ float lds[BLK * ROWF];   // 51712 B

    const int tid = threadIdx.x;
    const int b0  = blockIdx.x * BLK;
    const int b   = b0 + tid;           // BATCH % BLK == 0: no clamp needed

    const float4* c4 = (const float4*)(coef + (size_t)b * 12);
    const float4 ca0 = c4[0];   // c0 c1 c2 c3
    const float4 ca1 = c4[1];   // c4 c5 c6 c7
    const float4 ca2 = c4[2];   // c8 c9 c10 c11

    const float j0 = fabsf(ca0.x * ca0.w - ca0.y * ca0.z);
    const float j1 = fabsf(ca1.z * ca2.y - ca1.w * ca2.x);
    const float p  = j0 / (j0 + j1);

    // Issue ALL h loads up-front: ~100 outstanding loads/wave = max MLP.
    // Fully unrolled -> hv[] lives in registers (~140 VGPR total, no spill).
    float hv[ITERS];
    #pragma unroll
    for (int t = 0; t < ITERS; ++t) {
        hv[t] = h[(size_t)t * BATCH + b];
    }

    float2* row2 = (float2*)(lds + tid * ROWF);   // 808B pitch, 8B-aligned
    float x = 0.05f, y = 0.05f;
    row2[0] = make_float2(x, y);

    #pragma unroll
    for (int t = 0; t < ITERS; ++t) {
        const float ht = hv[t];
        const bool useB = ht > p;
        const float m0 = useB ? ca1.z : ca0.x;
        const float m1 = useB ? ca1.w : ca0.y;
        const float m2 = useB ? ca2.x : ca0.z;
        const float m3 = useB ? ca2.y : ca0.w;
        const float m4 = useB ? ca2.z : ca1.x;
        const float m5 = useB ? ca2.w : ca1.y;
        const float xn = fmaf(m0, x, fmaf(m1, y, m4));
        const float yn = fmaf(m2, x, fmaf(m3, y, m5));
        x = xn; y = yn;
        row2[t + 1] = make_float2(x, y);          // ds_write_b64
    }

    __syncthreads();   // single-wave block: cheap; publishes LDS

    // Contiguous sweep: block's output span [b0*808, b0*808 + 51712) is
    // byte-identical to lds[0..51712). 64B-aligned base, dwordx4, full lines.
    const float4* lsrc = (const float4*)lds;
    float4* dst = (float4*)(out + (size_t)b0 * ROWF);
    #pragma unroll
    for (int r = 0; r < FULLR; ++r) {
        dst[r * 64 + tid] = lsrc[r * 64 + tid];   // ds_read_b128 + store_dwordx4
    }
    if (tid < TAILV) {
        dst[FULLR * 64 + tid] = lsrc[FULLR * 64 + tid];
    }
}

extern "C" void kernel_launch(void* const* d_in, const int* in_sizes, int n_in,
                              void* d_out, int out_size, void* d_ws, size_t ws_size,
                              hipStream_t stream) {
    const float* coef = (const float*)d_in[0];   // (BATCH, 12) f32
    const float* h    = (const float*)d_in[1];   // (ITERS, BATCH) f32
    float* out        = (float*)d_out;           // (BATCH, 101, 2) f32

    const int grid = BATCH / BLK;                // 3125 exact
    ifs_traj_kernel<<<grid, BLK, 0, stream>>>(coef, h, out);
}